// Round 8
// baseline (280.110 us; speedup 1.0000x reference)
//
#include <hip/hip_runtime.h>
#include <cstddef>

#define NN 25600
#define BB 64
#define NPG 400
#define KK 16
#define LL 4

typedef _Float16 half_t;
typedef _Float16 h8 __attribute__((ext_vector_type(8)));
typedef _Float16 h4 __attribute__((ext_vector_type(4)));
typedef _Float16 h2 __attribute__((ext_vector_type(2)));
typedef float f32x4 __attribute__((ext_vector_type(4)));

// ---------------- weight prep: split-fp16 weights in MFMA FRAGMENT order ----
// WpreH/L (per layer, 32768 halves): frag idx ((c16*4 + kc)*64 + lane)*8 + j
//   c16 0..7 = A-side (Wp[:, :128]), c16 8..15 = B-side (Wp[:, 128:]).
// WpostH/L (per layer, 65536 halves): frag idx ((c16*16 + kc)*64 + lane)*8 + j
//   of the combined 128x512 post-weight, k-order [h | mean/16+s | mx | dir].
__global__ __launch_bounds__(256) void prep_k(const float* __restrict__ preW,
                                              const float* __restrict__ preb,
                                              const float* __restrict__ postW,
                                              half_t* __restrict__ WpreH,
                                              half_t* __restrict__ WpreL,
                                              float* __restrict__ bpre,
                                              half_t* __restrict__ WpostH,
                                              half_t* __restrict__ WpostL) {
  int idx = blockIdx.x * 256 + threadIdx.x;
  const int n1 = LL * 256 * 128;          // 131072
  const int n2 = n1 + LL * 256;           // +1024
  const int n3 = n2 + LL * 128 * 512;     // +262144
  if (idx < n1) {
    int l = idx / 32768;
    int q = idx % 32768;
    int j = q & 7, lane = (q >> 3) & 63, kc = (q >> 9) & 3, c16 = q >> 11;  // c16 0..15
    int col = c16 * 16 + (lane & 15);
    int k = kc * 32 + (lane >> 4) * 8 + j;
    float v = (col < 128) ? preW[(size_t)l * 32768 + (size_t)col * 256 + k]
                          : preW[(size_t)l * 32768 + (size_t)(col - 128) * 256 + 128 + k];
    half_t hi = (half_t)v;
    WpreH[idx] = hi;
    WpreL[idx] = (half_t)(v - (float)hi);
  } else if (idx < n2) {
    int r = idx - n1;
    int l = r / 256, o = r % 256;
    bpre[r] = (o < 128) ? 0.f : preb[l * 128 + (o - 128)];
  } else if (idx < n3) {
    int r = idx - n2;
    int l = r / 65536;
    int q = r % 65536;
    int j = q & 7, lane = (q >> 3) & 63, kc = (q >> 9) & 15, c16 = q >> 13;  // c16 0..7
    int col = c16 * 16 + (lane & 15);
    int k = kc * 32 + (lane >> 4) * 8 + j;
    int jblk = k >> 7, kk = k & 127;
    const float* base = postW + (size_t)l * 128 * 640 + (size_t)col * 640;
    float v;
    if (jblk == 0)      v = base[kk];
    else if (jblk == 1) v = base[128 + kk] * (1.f / 16.f) + base[256 + kk];
    else if (jblk == 2) v = base[384 + kk];
    else                v = base[512 + kk];
    half_t hi = (half_t)v;
    WpostH[r] = hi;
    WpostL[r] = (half_t)(v - (float)hi);
  }
}

// ---------------- embed gather: Hh/Hl (N x 128 split f16) ------------------
__global__ __launch_bounds__(256) void embed_k(const int* __restrict__ nf,
                                               const float* __restrict__ emb,
                                               half_t* __restrict__ Hh,
                                               half_t* __restrict__ Hl) {
  int idx = blockIdx.x * 256 + threadIdx.x;  // over N*32 float4s
  int n = idx >> 5;
  int d4 = idx & 31;
  int a = nf[n];
  float4 v = *(const float4*)(emb + (size_t)a * 128 + d4 * 4);
  h4 hi, lo;
  const float* vp = &v.x;
#pragma unroll
  for (int j = 0; j < 4; ++j) {
    half_t h = (half_t)vp[j];
    hi[j] = h;
    lo[j] = (half_t)(vp[j] - (float)h);
  }
  *(h4*)(Hh + (size_t)n * 128 + d4 * 4) = hi;
  *(h4*)(Hl + (size_t)n * 128 + d4 * 4) = lo;
}

// ---------------- pre-GEMM (A-side only): preA[N x 128] = Hcat @ WpA^T -----
// bias is zero for the A-side by construction. grid (400), XCD-swizzled.
__global__ __launch_bounds__(256) void pre_gemm_k(const half_t* __restrict__ Ah_g,
                                                  const half_t* __restrict__ Al_g,
                                                  const half_t* __restrict__ Wh_g,
                                                  const half_t* __restrict__ Wl_g,
                                                  float* __restrict__ preA) {
  __shared__ half_t Ahs[64][132];
  __shared__ half_t Als[64][132];
  const int tid = threadIdx.x;
  const int bid = blockIdx.x;                      // 0..399
  const int swz = (bid & 7) * 50 + (bid >> 3);     // XCD-contiguous rows
  const int r0 = swz * 64;
  const int wid = tid >> 6, lane = tid & 63;
  const int wm = wid >> 1, wn = wid & 1;
  const int lr = lane & 15, lk = (lane >> 4) * 8;
  f32x4 acc[2][4] = {};

  // stage full A tile (64 x 128, hi+lo)
  {
    const int row = tid >> 2;
#pragma unroll
    for (int s = 0; s < 4; ++s) {
      const int koff = (tid & 3) * 8 + s * 32;
      const size_t g = (size_t)(r0 + row) * 128 + koff;
      *(h8*)&Ahs[row][koff] = *(const h8*)(Ah_g + g);
      *(h8*)&Als[row][koff] = *(const h8*)(Al_g + g);
    }
  }
  __syncthreads();

#pragma unroll
  for (int kc = 0; kc < 4; ++kc) {
    h8 af[2][2];
#pragma unroll
    for (int mi = 0; mi < 2; ++mi) {
      const int r = wm * 32 + mi * 16 + lr;
      af[mi][0] = *(const h8*)&Ahs[r][kc * 32 + lk];
      af[mi][1] = *(const h8*)&Als[r][kc * 32 + lk];
    }
#pragma unroll
    for (int nj = 0; nj < 4; ++nj) {
      const size_t fi = ((size_t)((wn * 4 + nj) * 4 + kc) * 64 + lane) * 8;
      const h8 b0v = *(const h8*)(Wh_g + fi);
      const h8 b1v = *(const h8*)(Wl_g + fi);
#pragma unroll
      for (int mi = 0; mi < 2; ++mi) {
        acc[mi][nj] = __builtin_amdgcn_mfma_f32_16x16x32_f16(af[mi][0], b0v, acc[mi][nj], 0, 0, 0);
        acc[mi][nj] = __builtin_amdgcn_mfma_f32_16x16x32_f16(af[mi][0], b1v, acc[mi][nj], 0, 0, 0);
        acc[mi][nj] = __builtin_amdgcn_mfma_f32_16x16x32_f16(af[mi][1], b0v, acc[mi][nj], 0, 0, 0);
      }
    }
  }
  // epilogue: C/D layout col=lane&15, row=(lane>>4)*4+q
#pragma unroll
  for (int mi = 0; mi < 2; ++mi) {
    const int rowb = r0 + wm * 32 + mi * 16 + (lane >> 4) * 4;
#pragma unroll
    for (int nj = 0; nj < 4; ++nj) {
      const int col = wn * 64 + nj * 16 + lr;
#pragma unroll
      for (int q = 0; q < 4; ++q) {
        preA[(size_t)(rowb + q) * 128 + col] = acc[mi][nj][q];
      }
    }
  }
}

// ---------------- fused B-side pre-GEMM + edge-agg + post-GEMM -------------
// block = 16 nodes, 4 waves. Step A: b = Hcat(16 rows) @ WpB^T + bias -> LDS
// (reuses the prefetched afh fragments). Step B: gather preA rows (L2/L3-hot)
// and aggregate s/mx/dir into LDS split-f16. Step C: K=512 MFMA + epilogue
// writing the new h as split-f16 (no f32 h anywhere).
__global__ __launch_bounds__(256) void agg_post_k(const float* __restrict__ preA,  // N x 128
                                                  const int* __restrict__ src,
                                                  const float* __restrict__ eig,   // E x 2
                                                  const half_t* __restrict__ WpHg, // pre frag-major
                                                  const half_t* __restrict__ WpLg,
                                                  const float* __restrict__ bpre128, // 128 (B-side bias)
                                                  half_t* __restrict__ Hh,         // N x 128 (in/out)
                                                  half_t* __restrict__ Hl,
                                                  const half_t* __restrict__ Wh,   // post frag-major
                                                  const half_t* __restrict__ Wl,
                                                  const float* __restrict__ bias,  // 128
                                                  const float* __restrict__ snorm) {
  __shared__ half_t Ah[16][392];
  __shared__ half_t Al[16][392];
  __shared__ float bsh[16][132];
  const int tid = threadIdx.x;
  const int bid = blockIdx.x;                       // 0..1599
  const int swz = (bid & 7) * 200 + (bid >> 3);     // XCD-contiguous nodes
  const int r0 = swz * 16;
  const int wid = tid >> 6, lane = tid & 63;
  const int wn = wid;                               // 4 waves split 128 cols
  const int lr = lane & 15, lk = (lane >> 4) * 8;
  const int d0 = 2 * lane;

  // prefetch h fragments for this block's 16 rows (used by b-GEMM, phase-2 kc<4)
  const int frow = r0 + lr;
  h8 afh[4][2];
#pragma unroll
  for (int hc = 0; hc < 4; ++hc) {
    afh[hc][0] = *(const h8*)(Hh + (size_t)frow * 128 + hc * 32 + lk);
    afh[hc][1] = *(const h8*)(Hl + (size_t)frow * 128 + hc * 32 + lk);
  }

  // ---- step A: b = Hcat @ WpB^T + bias(B-side) -> bsh[16][128] ----
  {
    f32x4 bacc[2] = {};
#pragma unroll
    for (int kc = 0; kc < 4; ++kc) {
#pragma unroll
      for (int nj = 0; nj < 2; ++nj) {
        const size_t fi = ((size_t)((8 + wn * 2 + nj) * 4 + kc) * 64 + lane) * 8;
        const h8 b0v = *(const h8*)(WpHg + fi);
        const h8 b1v = *(const h8*)(WpLg + fi);
        bacc[nj] = __builtin_amdgcn_mfma_f32_16x16x32_f16(afh[kc][0], b0v, bacc[nj], 0, 0, 0);
        bacc[nj] = __builtin_amdgcn_mfma_f32_16x16x32_f16(afh[kc][0], b1v, bacc[nj], 0, 0, 0);
        bacc[nj] = __builtin_amdgcn_mfma_f32_16x16x32_f16(afh[kc][1], b0v, bacc[nj], 0, 0, 0);
      }
    }
    const int rowb = (lane >> 4) * 4;
#pragma unroll
    for (int nj = 0; nj < 2; ++nj) {
      const int col = (wn * 2 + nj) * 16 + lr;
      const float bv = bpre128[col];
#pragma unroll
      for (int q = 0; q < 4; ++q) {
        bsh[rowb + q][col] = bacc[nj][q] + bv;
      }
    }
  }
  __syncthreads();

  // ---- step B: aggregation, 4 nodes per wave ----
  for (int i = 0; i < 4; ++i) {
    const int lrow = wid * 4 + i;
    const int n = r0 + lrow;
    int sv[KK];
    float wv[KK];
    {
      const int4* sp4 = (const int4*)(src + (size_t)n * KK);
      const float4* ep4 = (const float4*)(eig + (size_t)n * KK * 2);
#pragma unroll
      for (int t = 0; t < 4; ++t) {
        const int4 s4 = sp4[t];
        sv[4 * t + 0] = s4.x;
        sv[4 * t + 1] = s4.y;
        sv[4 * t + 2] = s4.z;
        sv[4 * t + 3] = s4.w;
      }
#pragma unroll
      for (int t = 0; t < 8; ++t) {
        const float4 e4 = ep4[t];
        wv[2 * t + 0] = e4.y;
        wv[2 * t + 1] = e4.w;
      }
    }
    float denom = 0.f;
#pragma unroll
    for (int e = 0; e < KK; ++e) denom += fabsf(wv[e]);
    denom += 1e-8f;
    const float inv = 1.f / denom;
    float sum_ew = 0.f;
#pragma unroll
    for (int e = 0; e < KK; ++e) {
      wv[e] *= inv;
      sum_ew += wv[e];
    }
    float sA0 = 0.f, sA1 = 0.f, wA0 = 0.f, wA1 = 0.f;
    float mA0 = -3.402823466e+38f, mA1 = -3.402823466e+38f;
#pragma unroll
    for (int e = 0; e < KK; ++e) {
      const float2 a = *(const float2*)(preA + (size_t)sv[e] * 128 + d0);
      sA0 += a.x;
      sA1 += a.y;
      wA0 = fmaf(wv[e], a.x, wA0);
      wA1 = fmaf(wv[e], a.y, wA1);
      mA0 = fmaxf(mA0, a.x);
      mA1 = fmaxf(mA1, a.y);
    }
    const float2 b = {bsh[lrow][d0], bsh[lrow][d0 + 1]};
    const h2 hh2 = *(const h2*)(Hh + (size_t)n * 128 + d0);
    const h2 hl2 = *(const h2*)(Hl + (size_t)n * 128 + d0);
    const float hx = (float)hh2[0] + (float)hl2[0];
    const float hy = (float)hh2[1] + (float)hl2[1];
    auto wr2 = [&](int kcol, float v0, float v1) {
      h2 hi, lo;
      hi[0] = (half_t)v0;
      hi[1] = (half_t)v1;
      lo[0] = (half_t)(v0 - (float)hi[0]);
      lo[1] = (half_t)(v1 - (float)hi[1]);
      *(h2*)&Ah[lrow][kcol] = hi;
      *(h2*)&Al[lrow][kcol] = lo;
    };
    wr2(d0, sA0 + 16.f * b.x, sA1 + 16.f * b.y);
    wr2(128 + d0, mA0 + b.x, mA1 + b.y);
    wr2(256 + d0, fabsf(wA0 + sum_ew * (b.x - hx)), fabsf(wA1 + sum_ew * (b.y - hy)));
  }
  __syncthreads();

  // ---- step C: GEMM over K=512, wave tile 16 x 32 ----
  f32x4 acc[2] = {};
#pragma unroll
  for (int kc = 0; kc < 16; ++kc) {
    h8 a0, a1;
    if (kc < 4) {
      a0 = afh[kc & 3][0];
      a1 = afh[kc & 3][1];
    } else {
      a0 = *(const h8*)&Ah[lr][(kc - 4) * 32 + lk];
      a1 = *(const h8*)&Al[lr][(kc - 4) * 32 + lk];
    }
#pragma unroll
    for (int nj = 0; nj < 2; ++nj) {
      const size_t fi = ((size_t)((wn * 2 + nj) * 16 + kc) * 64 + lane) * 8;
      const h8 b0v = *(const h8*)(Wh + fi);
      const h8 b1v = *(const h8*)(Wl + fi);
      acc[nj] = __builtin_amdgcn_mfma_f32_16x16x32_f16(a0, b0v, acc[nj], 0, 0, 0);
      acc[nj] = __builtin_amdgcn_mfma_f32_16x16x32_f16(a0, b1v, acc[nj], 0, 0, 0);
      acc[nj] = __builtin_amdgcn_mfma_f32_16x16x32_f16(a1, b0v, acc[nj], 0, 0, 0);
    }
  }

  // ---- epilogue: hn = h_old + relu((acc+bias)*snorm); write split-f16 -----
  const int rowb = r0 + (lane >> 4) * 4;
#pragma unroll
  for (int nj = 0; nj < 2; ++nj) {
    const int col = wn * 32 + nj * 16 + lr;
    const float bv = bias[col];
#pragma unroll
    for (int q = 0; q < 4; ++q) {
      const int r = rowb + q;
      float a = acc[nj][q] + bv;
      a *= snorm[r];
      a = fmaxf(a, 0.f);
      const size_t off = (size_t)r * 128 + col;
      const float hold = (float)Hh[off] + (float)Hl[off];
      const float hn = hold + a;
      const half_t hi = (half_t)hn;
      Hh[off] = hi;
      Hl[off] = (half_t)(hn - (float)hi);
    }
  }
}

// ---------------- fused graph-mean + readout MLP (64 blocks) ---------------
__global__ __launch_bounds__(256) void reduce_mlp_k(const half_t* __restrict__ Hh,
                                                    const half_t* __restrict__ Hl,
                                                    const float* __restrict__ W0, const float* __restrict__ b0,
                                                    const float* __restrict__ W1, const float* __restrict__ b1,
                                                    const float* __restrict__ W2, const float* __restrict__ b2,
                                                    float* __restrict__ out) {
  __shared__ float hgs[128];
  __shared__ float red[128];
  __shared__ float y0s[64];
  __shared__ float y1s[32];
  __shared__ float wb[64 * 130];
  const int g = blockIdx.x;
  const int t = threadIdx.x;
  {
    const int d = t & 127, hf = t >> 7;
    const size_t base = ((size_t)g * NPG + (size_t)hf * 200) * 128 + d;
    float acc = 0.f;
    for (int i = 0; i < 200; ++i) {
      const size_t off = base + (size_t)i * 128;
      acc += (float)Hh[off] + (float)Hl[off];
    }
    if (hf) red[d] = acc;
    __syncthreads();
    if (!hf) hgs[d] = (acc + red[d]) * (1.f / (float)NPG);
  }
  __syncthreads();
  for (int idx = t; idx < 64 * 128; idx += 256) {
    wb[(idx >> 7) * 130 + (idx & 127)] = W0[idx];
  }
  __syncthreads();
  if (t < 64) {
    float a = b0[t];
    const float* w = &wb[t * 130];
    for (int k = 0; k < 128; ++k) a = fmaf(hgs[k], w[k], a);
    y0s[t] = fmaxf(a, 0.f);
  }
  __syncthreads();
  for (int idx = t; idx < 32 * 64; idx += 256) {
    wb[(idx >> 6) * 66 + (idx & 63)] = W1[idx];
  }
  __syncthreads();
  if (t < 32) {
    float a = b1[t];
    const float* w = &wb[t * 66];
    for (int k = 0; k < 64; ++k) a = fmaf(y0s[k], w[k], a);
    y1s[t] = fmaxf(a, 0.f);
  }
  __syncthreads();
  for (int idx = t; idx < 128 * 32; idx += 256) {
    wb[(idx >> 5) * 34 + (idx & 31)] = W2[idx];
  }
  __syncthreads();
  if (t < 128) {
    float a = b2[t];
    const float* w = &wb[t * 34];
    for (int k = 0; k < 32; ++k) a = fmaf(y1s[k], w[k], a);
    out[(size_t)g * 128 + t] = a;
  }
}

extern "C" void kernel_launch(void* const* d_in, const int* in_sizes, int n_in,
                              void* d_out, int out_size, void* d_ws, size_t ws_size,
                              hipStream_t stream) {
  const int* node_feat = (const int*)d_in[0];
  const int* src = (const int*)d_in[1];
  // d_in[2] = dst (repeat(arange(N),16)), unused
  const float* eig = (const float*)d_in[3];
  const float* snorm = (const float*)d_in[4];
  // d_in[5] = graph_ids, unused
  const float* emb = (const float*)d_in[6];
  const float* preW = (const float*)d_in[7];
  const float* preb = (const float*)d_in[8];
  const float* postW = (const float*)d_in[9];
  const float* postb = (const float*)d_in[10];
  const float* rW0 = (const float*)d_in[11];
  const float* rb0 = (const float*)d_in[12];
  const float* rW1 = (const float*)d_in[13];
  const float* rb1 = (const float*)d_in[14];
  const float* rW2 = (const float*)d_in[15];
  const float* rb2 = (const float*)d_in[16];
  float* out = (float*)d_out;

  half_t* Hh = (half_t*)d_ws;                        // N*128
  half_t* Hl = Hh + (size_t)NN * 128;                // N*128
  float* preA = (float*)(Hl + (size_t)NN * 128);     // N*128 f32 (gathered)
  half_t* WpreH = (half_t*)(preA + (size_t)NN * 128); // L*256*128 frag-major
  half_t* WpreL = WpreH + (size_t)LL * 32768;
  half_t* WpostH = WpreL + (size_t)LL * 32768;       // L*128*512 frag-major
  half_t* WpostL = WpostH + (size_t)LL * 65536;
  float* bpre = (float*)(WpostL + (size_t)LL * 65536); // L*256

  prep_k<<<1540, 256, 0, stream>>>(preW, preb, postW, WpreH, WpreL, bpre, WpostH, WpostL);
  embed_k<<<(NN * 32) / 256, 256, 0, stream>>>(node_feat, emb, Hh, Hl);

  for (int l = 0; l < LL; ++l) {
    pre_gemm_k<<<NN / 64, 256, 0, stream>>>(
        Hh, Hl, WpreH + (size_t)l * 32768, WpreL + (size_t)l * 32768, preA);
    agg_post_k<<<NN / 16, 256, 0, stream>>>(
        preA, src, eig,
        WpreH + (size_t)l * 32768, WpreL + (size_t)l * 32768,
        bpre + (size_t)l * 256 + 128,
        Hh, Hl,
        WpostH + (size_t)l * 65536, WpostL + (size_t)l * 65536,
        postb + (size_t)l * 128, snorm);
  }

  reduce_mlp_k<<<BB, 256, 0, stream>>>(Hh, Hl, rW0, rb0, rW1, rb1, rW2, rb2, out);
}

// Round 9
// 250.724 us; speedup vs baseline: 1.1172x; 1.1172x over previous
//
#include <hip/hip_runtime.h>
#include <cstddef>

#define NN 25600
#define BB 64
#define NPG 400
#define KK 16
#define LL 4

typedef _Float16 half_t;
typedef _Float16 h8 __attribute__((ext_vector_type(8)));
typedef _Float16 h4 __attribute__((ext_vector_type(4)));
typedef _Float16 h2 __attribute__((ext_vector_type(2)));
typedef float f32x4 __attribute__((ext_vector_type(4)));

#define GCAST(p) ((const __attribute__((address_space(1))) void*)(p))
#define SCAST(p) ((__attribute__((address_space(3))) void*)(p))

// ---------------- weight prep: split-fp16 weights in MFMA FRAGMENT order ----
__global__ __launch_bounds__(256) void prep_k(const float* __restrict__ preW,
                                              const float* __restrict__ preb,
                                              const float* __restrict__ postW,
                                              half_t* __restrict__ WpreH,
                                              half_t* __restrict__ WpreL,
                                              float* __restrict__ bpre,
                                              half_t* __restrict__ WpostH,
                                              half_t* __restrict__ WpostL) {
  int idx = blockIdx.x * 256 + threadIdx.x;
  const int n1 = LL * 256 * 128;          // 131072
  const int n2 = n1 + LL * 256;           // +1024
  const int n3 = n2 + LL * 128 * 512;     // +262144
  if (idx < n1) {
    int l = idx / 32768;
    int q = idx % 32768;
    int j = q & 7, lane = (q >> 3) & 63, kc = (q >> 9) & 3, c16 = q >> 11;  // c16 0..15
    int col = c16 * 16 + (lane & 15);
    int k = kc * 32 + (lane >> 4) * 8 + j;
    float v = (col < 128) ? preW[(size_t)l * 32768 + (size_t)col * 256 + k]
                          : preW[(size_t)l * 32768 + (size_t)(col - 128) * 256 + 128 + k];
    half_t hi = (half_t)v;
    WpreH[idx] = hi;
    WpreL[idx] = (half_t)(v - (float)hi);
  } else if (idx < n2) {
    int r = idx - n1;
    int l = r / 256, o = r % 256;
    bpre[r] = (o < 128) ? 0.f : preb[l * 128 + (o - 128)];
  } else if (idx < n3) {
    int r = idx - n2;
    int l = r / 65536;
    int q = r % 65536;
    int j = q & 7, lane = (q >> 3) & 63, kc = (q >> 9) & 15, c16 = q >> 13;  // c16 0..7
    int col = c16 * 16 + (lane & 15);
    int k = kc * 32 + (lane >> 4) * 8 + j;
    int jblk = k >> 7, kk = k & 127;
    const float* base = postW + (size_t)l * 128 * 640 + (size_t)col * 640;
    float v;
    if (jblk == 0)      v = base[kk];
    else if (jblk == 1) v = base[128 + kk] * (1.f / 16.f) + base[256 + kk];
    else if (jblk == 2) v = base[384 + kk];
    else                v = base[512 + kk];
    half_t hi = (half_t)v;
    WpostH[r] = hi;
    WpostL[r] = (half_t)(v - (float)hi);
  }
}

// ---------------- embed gather: Hh/Hl (N x 128 split f16) ------------------
__global__ __launch_bounds__(256) void embed_k(const int* __restrict__ nf,
                                               const float* __restrict__ emb,
                                               half_t* __restrict__ Hh,
                                               half_t* __restrict__ Hl) {
  int idx = blockIdx.x * 256 + threadIdx.x;  // over N*32 float4s
  int n = idx >> 5;
  int d4 = idx & 31;
  int a = nf[n];
  float4 v = *(const float4*)(emb + (size_t)a * 128 + d4 * 4);
  h4 hi, lo;
  const float* vp = &v.x;
#pragma unroll
  for (int j = 0; j < 4; ++j) {
    half_t h = (half_t)vp[j];
    hi[j] = h;
    lo[j] = (half_t)(vp[j] - (float)h);
  }
  *(h4*)(Hh + (size_t)n * 128 + d4 * 4) = hi;
  *(h4*)(Hl + (size_t)n * 128 + d4 * 4) = lo;
}

// ---------------- pre-GEMM (A-side only): preA[N x 128] = Hcat @ WpA^T -----
__global__ __launch_bounds__(256) void pre_gemm_k(const half_t* __restrict__ Ah_g,
                                                  const half_t* __restrict__ Al_g,
                                                  const half_t* __restrict__ Wh_g,
                                                  const half_t* __restrict__ Wl_g,
                                                  float* __restrict__ preA) {
  __shared__ half_t Ahs[64][132];
  __shared__ half_t Als[64][132];
  const int tid = threadIdx.x;
  const int bid = blockIdx.x;                      // 0..399
  const int swz = (bid & 7) * 50 + (bid >> 3);     // XCD-contiguous rows
  const int r0 = swz * 64;
  const int wid = tid >> 6, lane = tid & 63;
  const int wm = wid >> 1, wn = wid & 1;
  const int lr = lane & 15, lk = (lane >> 4) * 8;
  f32x4 acc[2][4] = {};

  // stage full A tile (64 x 128, hi+lo)
  {
    const int row = tid >> 2;
#pragma unroll
    for (int s = 0; s < 4; ++s) {
      const int koff = (tid & 3) * 8 + s * 32;
      const size_t g = (size_t)(r0 + row) * 128 + koff;
      *(h8*)&Ahs[row][koff] = *(const h8*)(Ah_g + g);
      *(h8*)&Als[row][koff] = *(const h8*)(Al_g + g);
    }
  }
  __syncthreads();

#pragma unroll
  for (int kc = 0; kc < 4; ++kc) {
    h8 af[2][2];
#pragma unroll
    for (int mi = 0; mi < 2; ++mi) {
      const int r = wm * 32 + mi * 16 + lr;
      af[mi][0] = *(const h8*)&Ahs[r][kc * 32 + lk];
      af[mi][1] = *(const h8*)&Als[r][kc * 32 + lk];
    }
#pragma unroll
    for (int nj = 0; nj < 4; ++nj) {
      const size_t fi = ((size_t)((wn * 4 + nj) * 4 + kc) * 64 + lane) * 8;
      const h8 b0v = *(const h8*)(Wh_g + fi);
      const h8 b1v = *(const h8*)(Wl_g + fi);
#pragma unroll
      for (int mi = 0; mi < 2; ++mi) {
        acc[mi][nj] = __builtin_amdgcn_mfma_f32_16x16x32_f16(af[mi][0], b0v, acc[mi][nj], 0, 0, 0);
        acc[mi][nj] = __builtin_amdgcn_mfma_f32_16x16x32_f16(af[mi][0], b1v, acc[mi][nj], 0, 0, 0);
        acc[mi][nj] = __builtin_amdgcn_mfma_f32_16x16x32_f16(af[mi][1], b0v, acc[mi][nj], 0, 0, 0);
      }
    }
  }
  // epilogue: C/D layout col=lane&15, row=(lane>>4)*4+q
#pragma unroll
  for (int mi = 0; mi < 2; ++mi) {
    const int rowb = r0 + wm * 32 + mi * 16 + (lane >> 4) * 4;
#pragma unroll
    for (int nj = 0; nj < 4; ++nj) {
      const int col = wn * 64 + nj * 16 + lr;
#pragma unroll
      for (int q = 0; q < 4; ++q) {
        preA[(size_t)(rowb + q) * 128 + col] = acc[mi][nj][q];
      }
    }
  }
}

// ---------------- fused B-side pre-GEMM + edge-agg + post-GEMM -------------
// block = 16 nodes, 4 waves. Gathers staged via async global_load_lds (no
// VGPR round-trip, vmcnt-counted): per node, 2 chunks of 8 rows (4 instrs,
// 16B/lane, lanes 0-31 -> row e, 32-63 -> row e+1), wait, reduce from LDS.
__global__ __launch_bounds__(256, 2) void agg_post_k(const float* __restrict__ preA,  // N x 128
                                                     const int* __restrict__ src,
                                                     const float* __restrict__ eig,   // E x 2
                                                     const half_t* __restrict__ WpHg, // pre frag-major
                                                     const half_t* __restrict__ WpLg,
                                                     const float* __restrict__ bpre128, // B-side bias
                                                     half_t* __restrict__ Hh,         // N x 128 (in/out)
                                                     half_t* __restrict__ Hl,
                                                     const half_t* __restrict__ Wh,   // post frag-major
                                                     const half_t* __restrict__ Wl,
                                                     const float* __restrict__ bias,  // 128
                                                     const float* __restrict__ snorm) {
  __shared__ half_t Ah[16][392];
  __shared__ half_t Al[16][392];
  __shared__ float bsh[16][132];
  __shared__ float stage[4][8][128];               // per-wave gather staging
  const int tid = threadIdx.x;
  const int bid = blockIdx.x;                       // 0..1599
  const int swz = (bid & 7) * 200 + (bid >> 3);     // XCD-contiguous nodes
  const int r0 = swz * 16;
  const int wid = tid >> 6, lane = tid & 63;
  const int wn = wid;                               // 4 waves split 128 cols
  const int lr = lane & 15, lk = (lane >> 4) * 8;
  const int d0 = 2 * lane;
  const int glane = (lane & 31) * 4;                // float offset within row
  const int gsel = lane >> 5;                       // 0/1: which row of the pair

  // prefetch h fragments for this block's 16 rows
  const int frow = r0 + lr;
  h8 afh[4][2];
#pragma unroll
  for (int hc = 0; hc < 4; ++hc) {
    afh[hc][0] = *(const h8*)(Hh + (size_t)frow * 128 + hc * 32 + lk);
    afh[hc][1] = *(const h8*)(Hl + (size_t)frow * 128 + hc * 32 + lk);
  }

  // ---- step A: b = Hcat @ WpB^T + bias(B-side) -> bsh[16][128] ----
  {
    f32x4 bacc[2] = {};
#pragma unroll
    for (int kc = 0; kc < 4; ++kc) {
#pragma unroll
      for (int nj = 0; nj < 2; ++nj) {
        const size_t fi = ((size_t)((8 + wn * 2 + nj) * 4 + kc) * 64 + lane) * 8;
        const h8 b0v = *(const h8*)(WpHg + fi);
        const h8 b1v = *(const h8*)(WpLg + fi);
        bacc[nj] = __builtin_amdgcn_mfma_f32_16x16x32_f16(afh[kc][0], b0v, bacc[nj], 0, 0, 0);
        bacc[nj] = __builtin_amdgcn_mfma_f32_16x16x32_f16(afh[kc][0], b1v, bacc[nj], 0, 0, 0);
        bacc[nj] = __builtin_amdgcn_mfma_f32_16x16x32_f16(afh[kc][1], b0v, bacc[nj], 0, 0, 0);
      }
    }
    const int rowb = (lane >> 4) * 4;
#pragma unroll
    for (int nj = 0; nj < 2; ++nj) {
      const int col = (wn * 2 + nj) * 16 + lr;
      const float bv = bpre128[col];
#pragma unroll
      for (int q = 0; q < 4; ++q) {
        bsh[rowb + q][col] = bacc[nj][q] + bv;
      }
    }
  }
  __syncthreads();

  // ---- step B: aggregation, 4 nodes per wave, async-staged gathers ----
  for (int i = 0; i < 4; ++i) {
    const int lrow = wid * 4 + i;
    const int n = r0 + lrow;
    int sv[KK];
    float wv[KK];
    {
      const int4* sp4 = (const int4*)(src + (size_t)n * KK);
      const float4* ep4 = (const float4*)(eig + (size_t)n * KK * 2);
#pragma unroll
      for (int t = 0; t < 4; ++t) {
        const int4 s4 = sp4[t];
        sv[4 * t + 0] = s4.x;
        sv[4 * t + 1] = s4.y;
        sv[4 * t + 2] = s4.z;
        sv[4 * t + 3] = s4.w;
      }
#pragma unroll
      for (int t = 0; t < 8; ++t) {
        const float4 e4 = ep4[t];
        wv[2 * t + 0] = e4.y;
        wv[2 * t + 1] = e4.w;
      }
    }
    // issue chunk 0 (rows 0..7) as 4 DMA instructions
#pragma unroll
    for (int c = 0; c < 4; ++c) {
      const int e = 2 * c + gsel;
      const float* gp = preA + (size_t)sv[e] * 128 + glane;
      __builtin_amdgcn_global_load_lds(GCAST(gp), SCAST(&stage[wid][2 * c][0]), 16, 0, 0);
    }
    // weights (VALU overlaps DMA)
    float denom = 0.f;
#pragma unroll
    for (int e = 0; e < KK; ++e) denom += fabsf(wv[e]);
    denom += 1e-8f;
    const float inv = 1.f / denom;
    float sum_ew = 0.f;
#pragma unroll
    for (int e = 0; e < KK; ++e) {
      wv[e] *= inv;
      sum_ew += wv[e];
    }
    float sA0 = 0.f, sA1 = 0.f, wA0 = 0.f, wA1 = 0.f;
    float mA0 = -3.402823466e+38f, mA1 = -3.402823466e+38f;
    asm volatile("s_waitcnt vmcnt(0)" ::: "memory");
#pragma unroll
    for (int e = 0; e < 8; ++e) {
      const float2 a = *(const float2*)&stage[wid][e][d0];
      sA0 += a.x;
      sA1 += a.y;
      wA0 = fmaf(wv[e], a.x, wA0);
      wA1 = fmaf(wv[e], a.y, wA1);
      mA0 = fmaxf(mA0, a.x);
      mA1 = fmaxf(mA1, a.y);
    }
    // issue chunk 1 (rows 8..15)
#pragma unroll
    for (int c = 0; c < 4; ++c) {
      const int e = 8 + 2 * c + gsel;
      const float* gp = preA + (size_t)sv[e] * 128 + glane;
      __builtin_amdgcn_global_load_lds(GCAST(gp), SCAST(&stage[wid][2 * c][0]), 16, 0, 0);
    }
    asm volatile("s_waitcnt vmcnt(0)" ::: "memory");
#pragma unroll
    for (int e = 0; e < 8; ++e) {
      const float2 a = *(const float2*)&stage[wid][e][d0];
      const float w = wv[8 + e];
      sA0 += a.x;
      sA1 += a.y;
      wA0 = fmaf(w, a.x, wA0);
      wA1 = fmaf(w, a.y, wA1);
      mA0 = fmaxf(mA0, a.x);
      mA1 = fmaxf(mA1, a.y);
    }
    const float2 b = {bsh[lrow][d0], bsh[lrow][d0 + 1]};
    const h2 hh2 = *(const h2*)(Hh + (size_t)n * 128 + d0);
    const h2 hl2 = *(const h2*)(Hl + (size_t)n * 128 + d0);
    const float hx = (float)hh2[0] + (float)hl2[0];
    const float hy = (float)hh2[1] + (float)hl2[1];
    auto wr2 = [&](int kcol, float v0, float v1) {
      h2 hi, lo;
      hi[0] = (half_t)v0;
      hi[1] = (half_t)v1;
      lo[0] = (half_t)(v0 - (float)hi[0]);
      lo[1] = (half_t)(v1 - (float)hi[1]);
      *(h2*)&Ah[lrow][kcol] = hi;
      *(h2*)&Al[lrow][kcol] = lo;
    };
    wr2(d0, sA0 + 16.f * b.x, sA1 + 16.f * b.y);
    wr2(128 + d0, mA0 + b.x, mA1 + b.y);
    wr2(256 + d0, fabsf(wA0 + sum_ew * (b.x - hx)), fabsf(wA1 + sum_ew * (b.y - hy)));
  }
  __syncthreads();

  // ---- step C: GEMM over K=512, wave tile 16 x 32 ----
  f32x4 acc[2] = {};
#pragma unroll
  for (int kc = 0; kc < 16; ++kc) {
    h8 a0, a1;
    if (kc < 4) {
      a0 = afh[kc & 3][0];
      a1 = afh[kc & 3][1];
    } else {
      a0 = *(const h8*)&Ah[lr][(kc - 4) * 32 + lk];
      a1 = *(const h8*)&Al[lr][(kc - 4) * 32 + lk];
    }
#pragma unroll
    for (int nj = 0; nj < 2; ++nj) {
      const size_t fi = ((size_t)((wn * 2 + nj) * 16 + kc) * 64 + lane) * 8;
      const h8 b0v = *(const h8*)(Wh + fi);
      const h8 b1v = *(const h8*)(Wl + fi);
      acc[nj] = __builtin_amdgcn_mfma_f32_16x16x32_f16(a0, b0v, acc[nj], 0, 0, 0);
      acc[nj] = __builtin_amdgcn_mfma_f32_16x16x32_f16(a0, b1v, acc[nj], 0, 0, 0);
      acc[nj] = __builtin_amdgcn_mfma_f32_16x16x32_f16(a1, b0v, acc[nj], 0, 0, 0);
    }
  }

  // ---- epilogue: hn = h_old + relu((acc+bias)*snorm); write split-f16 -----
  const int rowb = r0 + (lane >> 4) * 4;
#pragma unroll
  for (int nj = 0; nj < 2; ++nj) {
    const int col = wn * 32 + nj * 16 + lr;
    const float bv = bias[col];
#pragma unroll
    for (int q = 0; q < 4; ++q) {
      const int r = rowb + q;
      float a = acc[nj][q] + bv;
      a *= snorm[r];
      a = fmaxf(a, 0.f);
      const size_t off = (size_t)r * 128 + col;
      const float hold = (float)Hh[off] + (float)Hl[off];
      const float hn = hold + a;
      const half_t hi = (half_t)hn;
      Hh[off] = hi;
      Hl[off] = (half_t)(hn - (float)hi);
    }
  }
}

// ---------------- fused graph-mean + readout MLP (64 blocks) ---------------
__global__ __launch_bounds__(256) void reduce_mlp_k(const half_t* __restrict__ Hh,
                                                    const half_t* __restrict__ Hl,
                                                    const float* __restrict__ W0, const float* __restrict__ b0,
                                                    const float* __restrict__ W1, const float* __restrict__ b1,
                                                    const float* __restrict__ W2, const float* __restrict__ b2,
                                                    float* __restrict__ out) {
  __shared__ float hgs[128];
  __shared__ float red[128];
  __shared__ float y0s[64];
  __shared__ float y1s[32];
  __shared__ float wb[64 * 130];
  const int g = blockIdx.x;
  const int t = threadIdx.x;
  {
    const int d = t & 127, hf = t >> 7;
    const size_t base = ((size_t)g * NPG + (size_t)hf * 200) * 128 + d;
    float acc = 0.f;
    for (int i = 0; i < 200; ++i) {
      const size_t off = base + (size_t)i * 128;
      acc += (float)Hh[off] + (float)Hl[off];
    }
    if (hf) red[d] = acc;
    __syncthreads();
    if (!hf) hgs[d] = (acc + red[d]) * (1.f / (float)NPG);
  }
  __syncthreads();
  for (int idx = t; idx < 64 * 128; idx += 256) {
    wb[(idx >> 7) * 130 + (idx & 127)] = W0[idx];
  }
  __syncthreads();
  if (t < 64) {
    float a = b0[t];
    const float* w = &wb[t * 130];
    for (int k = 0; k < 128; ++k) a = fmaf(hgs[k], w[k], a);
    y0s[t] = fmaxf(a, 0.f);
  }
  __syncthreads();
  for (int idx = t; idx < 32 * 64; idx += 256) {
    wb[(idx >> 6) * 66 + (idx & 63)] = W1[idx];
  }
  __syncthreads();
  if (t < 32) {
    float a = b1[t];
    const float* w = &wb[t * 66];
    for (int k = 0; k < 64; ++k) a = fmaf(y0s[k], w[k], a);
    y1s[t] = fmaxf(a, 0.f);
  }
  __syncthreads();
  for (int idx = t; idx < 128 * 32; idx += 256) {
    wb[(idx >> 5) * 34 + (idx & 31)] = W2[idx];
  }
  __syncthreads();
  if (t < 128) {
    float a = b2[t];
    const float* w = &wb[t * 34];
    for (int k = 0; k < 32; ++k) a = fmaf(y1s[k], w[k], a);
    out[(size_t)g * 128 + t] = a;
  }
}

extern "C" void kernel_launch(void* const* d_in, const int* in_sizes, int n_in,
                              void* d_out, int out_size, void* d_ws, size_t ws_size,
                              hipStream_t stream) {
  const int* node_feat = (const int*)d_in[0];
  const int* src = (const int*)d_in[1];
  // d_in[2] = dst (repeat(arange(N),16)), unused
  const float* eig = (const float*)d_in[3];
  const float* snorm = (const float*)d_in[4];
  // d_in[5] = graph_ids, unused
  const float* emb = (const float*)d_in[6];
  const float* preW = (const float*)d_in[7];
  const float* preb = (const float*)d_in[8];
  const float* postW = (const float*)d_in[9];
  const float* postb = (const float*)d_in[10];
  const float* rW0 = (const float*)d_in[11];
  const float* rb0 = (const float*)d_in[12];
  const float* rW1 = (const float*)d_in[13];
  const float* rb1 = (const float*)d_in[14];
  const float* rW2 = (const float*)d_in[15];
  const float* rb2 = (const float*)d_in[16];
  float* out = (float*)d_out;

  half_t* Hh = (half_t*)d_ws;                        // N*128
  half_t* Hl = Hh + (size_t)NN * 128;                // N*128
  float* preA = (float*)(Hl + (size_t)NN * 128);     // N*128 f32 (gathered)
  half_t* WpreH = (half_t*)(preA + (size_t)NN * 128); // L*256*128 frag-major
  half_t* WpreL = WpreH + (size_t)LL * 32768;
  half_t* WpostH = WpreL + (size_t)LL * 32768;       // L*128*512 frag-major
  half_t* WpostL = WpostH + (size_t)LL * 65536;
  float* bpre = (float*)(WpostL + (size_t)LL * 65536); // L*256

  prep_k<<<1540, 256, 0, stream>>>(preW, preb, postW, WpreH, WpreL, bpre, WpostH, WpostL);
  embed_k<<<(NN * 32) / 256, 256, 0, stream>>>(node_feat, emb, Hh, Hl);

  for (int l = 0; l < LL; ++l) {
    pre_gemm_k<<<NN / 64, 256, 0, stream>>>(
        Hh, Hl, WpreH + (size_t)l * 32768, WpreL + (size_t)l * 32768, preA);
    agg_post_k<<<NN / 16, 256, 0, stream>>>(
        preA, src, eig,
        WpreH + (size_t)l * 32768, WpreL + (size_t)l * 32768,
        bpre + (size_t)l * 256 + 128,
        Hh, Hl,
        WpostH + (size_t)l * 65536, WpostL + (size_t)l * 65536,
        postb + (size_t)l * 128, snorm);
  }

  reduce_mlp_k<<<BB, 256, 0, stream>>>(Hh, Hl, rW0, rb0, rW1, rb1, rW2, rb2, out);
}